// Round 2
// baseline (8164.726 us; speedup 1.0000x reference)
//
#include <hip/hip_runtime.h>
#include <math.h>

// Problem constants
#define HC 96
#define WC 96
#define CCH 64
#define BB 8
#define NL 8
#define IMG (HC*WC)                 // 9216
#define LSTRIDE (BB*CCH*IMG)        // 4,718,592 elements per layer tensor
#define EPS 1e-5f

// Conv tiling
#define TOC 16      // output channels per block
#define TROWS 6     // output rows per block (96/6 = 16 row groups)
#define ICCH 8      // input-channel chunk
#define SROWS (TROWS+2)
#define SNC 98      // staged cols (96 + 2 halo)
#define SCOLS 104   // padded LDS row stride

// ---------------------------------------------------------------------------
// Repack convT weights: Wt[l][o][c][k] = K[l][c][o][8-k]   (flip hw + swap io)
__global__ void repack_wt(const float* __restrict__ K, float* __restrict__ Wt){
  int idx = blockIdx.x*256 + threadIdx.x;
  if (idx >= NL*CCH*CCH*9) return;
  int k = idx % 9; int t = idx/9;
  int c = t % CCH; t /= CCH;
  int o = t % CCH; int l = t / CCH;
  Wt[idx] = K[ ((l*CCH + c)*CCH + o)*9 + (8-k) ];
}

// ---------------------------------------------------------------------------
// Fix-iteration 0 constant-folded: Z=0 -> layer output 0 -> Y_0=X0b, Y_7=X.
// Forward scan closed form, writes Yf for all 8 layers into the Z region.
__global__ void init_yf(const float* __restrict__ X, const float* __restrict__ X0,
                        float* __restrict__ zbase){
  int idx = blockIdx.x*256 + threadIdx.x;
  if (idx >= LSTRIDE) return;
  int chw = idx % (CCH*IMG);
  float x0 = X0[chw];
  float x  = X[idx];
  float yf = 0.f;
#pragma unroll
  for (int i=0;i<NL;i++){
    float ai = sqrtf((i+1.f)/(i+2.f));
    float bi = sqrtf((float)i/(float)(i+1));
    float y = 0.f;
    if (i==0)    y += x0;
    if (i==NL-1) y += x;
    yf = ai*(bi*yf + y);
    zbase[i*LSTRIDE + idx] = yf;
  }
}

// ---------------------------------------------------------------------------
// Backward scan (in place Yf -> Z), also emits out0 = Z[NL-1]
__global__ void back_scan(float* __restrict__ zbase, float* __restrict__ out0){
  int idx = blockIdx.x*256 + threadIdx.x;
  if (idx >= LSTRIDE) return;
  float c = 0.f;
#pragma unroll
  for (int i=NL-1;i>=0;i--){
    float ai = sqrtf((i+1.f)/(i+2.f));
    float z = ai*(ai*c + zbase[i*LSTRIDE + idx]);
    zbase[i*LSTRIDE + idx] = z;
    if (i==NL-1) out0[idx] = z;
    c = z;
  }
}

// ---------------------------------------------------------------------------
// Instance-norm stats: one block per (b,c); mean + rsqrt(var+eps)
__global__ __launch_bounds__(256) void inorm_stats(const float* __restrict__ dZ,
                                                   float2* __restrict__ stats){
  int bc = blockIdx.x;
  const float4* p = (const float4*)(dZ + (size_t)bc*IMG);
  float s = 0.f, s2 = 0.f;
  for (int i = threadIdx.x; i < IMG/4; i += 256){
    float4 v = p[i];
    s  += v.x + v.y + v.z + v.w;
    s2 += v.x*v.x + v.y*v.y + v.z*v.z + v.w*v.w;
  }
#pragma unroll
  for (int off=32; off>0; off>>=1){
    s  += __shfl_down(s, off);
    s2 += __shfl_down(s2, off);
  }
  __shared__ float as[4], as2[4];
  int w = threadIdx.x >> 6;
  if ((threadIdx.x & 63)==0){ as[w]=s; as2[w]=s2; }
  __syncthreads();
  if (threadIdx.x==0){
    s  = as[0]+as[1]+as[2]+as[3];
    s2 = as2[0]+as2[1]+as2[2]+as2[3];
    float m = s * (1.f/IMG);
    float v = s2 * (1.f/IMG) - m*m;
    if (v < 0.f) v = 0.f;
    stats[bc] = make_float2(m, rsqrtf(v + EPS));
  }
}

// ---------------------------------------------------------------------------
// Direct 3x3 conv, pad=1.
// MODE 0: plain input -> out (dZ)
// MODE 1: input transformed by (v-m)*inv then lrelu(0.2) during staging
//         (IN-BOUNDS PIXELS ONLY — the zero padding must remain zero, since
//          the reference normalizes first and pads the normalized tensor);
//         epilogue: y = -acc (+X if layer 7)(+X0 if layer 0);
//                   out = a*(b*yfprev + y)   (fused forward scan)
// Block: 256 threads = 16 oc-lanes x 16 col-groups (6 cols each).
// Tile: 16 oc x 6 rows x 96 cols. ic chunked by 8 through LDS.
template<int MODE>
__global__ __launch_bounds__(256) void conv3x3(
    const float* __restrict__ in, const float* __restrict__ Wgt,
    float* __restrict__ out,
    const float2* __restrict__ stats,
    const float* __restrict__ yfprev,
    const float* __restrict__ Xadd,
    const float* __restrict__ X0add,
    float a_i, float b_i)
{
  __shared__ float sIn[ICCH][SROWS][SCOLS];
  __shared__ float sK[ICCH][9][TOC];

  const int ocg  = blockIdx.x;   // 0..3
  const int rowg = blockIdx.y;   // 0..15
  const int b    = blockIdx.z;   // 0..7
  const int y0   = rowg*TROWS;
  const int oc0  = ocg*TOC;
  const int tid  = threadIdx.x;
  const int oc_l = tid & 15;
  const int px   = tid >> 4;     // 0..15
  const int x0   = px*6;

  float acc[TROWS][6];
#pragma unroll
  for (int r=0;r<TROWS;r++)
#pragma unroll
    for (int j=0;j<6;j++) acc[r][j] = 0.f;

  for (int cc=0; cc<CCH/ICCH; cc++){
    const int ic0 = cc*ICCH;
    __syncthreads();
    // stage input (with zero pad; MODE1: normalize + lrelu on REAL pixels only)
    for (int t = tid; t < ICCH*SROWS*SNC; t += 256){
      int c  = t % SNC;
      int r  = (t/SNC) % SROWS;
      int ic = t/(SNC*SROWS);
      int gy = y0 - 1 + r;
      int gx = c - 1;
      float v = 0.f;
      if (gy>=0 && gy<HC && gx>=0 && gx<WC){
        v = in[ ((size_t)(b*CCH + ic0+ic)*HC + gy)*WC + gx ];
        if (MODE==1){
          float2 st = stats[b*CCH + ic0 + ic];
          v = (v - st.x)*st.y;
          v = (v >= 0.f) ? v : 0.2f*v;
        }
      }
      sIn[ic][r][c] = v;
    }
    // stage weights: layout [ic][tap][oc] (oc contiguous -> conflict-free)
    for (int t = tid; t < ICCH*9*TOC; t += 256){
      int oc = t % TOC;
      int k  = (t/TOC) % 9;
      int ic = t/(TOC*9);
      sK[ic][k][oc] = Wgt[ ((size_t)(oc0+oc)*CCH + ic0+ic)*9 + k ];
    }
    __syncthreads();

    for (int ic=0; ic<ICCH; ic++){
      float w[9];
#pragma unroll
      for (int k=0;k<9;k++) w[k] = sK[ic][k][oc_l];
      float rows[3][8];
#pragma unroll
      for (int j=0;j<8;j++){ rows[0][j] = sIn[ic][0][x0+j];
                             rows[1][j] = sIn[ic][1][x0+j]; }
#pragma unroll
      for (int ry=0; ry<TROWS; ry++){
        const int i0 = ry%3, i1 = (ry+1)%3, i2 = (ry+2)%3;
#pragma unroll
        for (int j=0;j<8;j++) rows[i2][j] = sIn[ic][ry+2][x0+j];
#pragma unroll
        for (int j=0;j<6;j++){
          float s = acc[ry][j];
          s += w[0]*rows[i0][j] + w[1]*rows[i0][j+1] + w[2]*rows[i0][j+2];
          s += w[3]*rows[i1][j] + w[4]*rows[i1][j+1] + w[5]*rows[i1][j+2];
          s += w[6]*rows[i2][j] + w[7]*rows[i2][j+1] + w[8]*rows[i2][j+2];
          acc[ry][j] = s;
        }
      }
    }
  }

  // epilogue
#pragma unroll
  for (int ry=0; ry<TROWS; ry++){
    int y = y0 + ry;
#pragma unroll
    for (int j=0;j<6;j++){
      int x = x0 + j;
      size_t idx = ((size_t)(b*CCH + oc0 + oc_l)*HC + y)*WC + x;
      float v = acc[ry][j];
      if (MODE==0){
        out[idx] = v;
      } else {
        float yv = -v;
        if (Xadd)  yv += Xadd[idx];
        if (X0add) yv += X0add[(size_t)(oc0 + oc_l)*IMG + y*WC + x];
        float prev = (b_i != 0.f) ? yfprev[idx] : 0.f;
        out[idx] = a_i*(b_i*prev + yv);
      }
    }
  }
}

// ---------------------------------------------------------------------------
extern "C" void kernel_launch(void* const* d_in, const int* in_sizes, int n_in,
                              void* d_out, int out_size, void* d_ws, size_t ws_size,
                              hipStream_t stream) {
  const float* X  = (const float*)d_in[0];   // (8,64,96,96)
  const float* K  = (const float*)d_in[1];   // (8,64,64,3,3)
  const float* X0 = (const float*)d_in[2];   // (1,64,96,96)

  float* out0  = (float*)d_out;              // Z[-1]: LSTRIDE floats
  float* zbase = out0 + LSTRIDE;             // Z / Yf region: 8*LSTRIDE floats

  float* ws    = (float*)d_ws;
  float* Wt    = ws;                         // 294,912 floats
  float* dZ    = ws + NL*CCH*CCH*9;          // 4,718,592 floats
  float2* stats = (float2*)(dZ + LSTRIDE);   // 512 float2

  repack_wt<<<(NL*CCH*CCH*9 + 255)/256, 256, 0, stream>>>(K, Wt);

  // fix-iteration 0 (constant-folded) + backward scan
  init_yf<<<LSTRIDE/256, 256, 0, stream>>>(X, X0, zbase);
  back_scan<<<LSTRIDE/256, 256, 0, stream>>>(zbase, out0);

  dim3 cgrid(4, 16, 8);   // (oc groups, row groups, batch)
  for (int iter = 1; iter < 4; iter++){
    for (int l = 0; l < NL; l++){
      const float* Zl = zbase + (size_t)l*LSTRIDE;
      conv3x3<0><<<cgrid, 256, 0, stream>>>(
          Zl, K + (size_t)l*CCH*CCH*9, dZ,
          nullptr, nullptr, nullptr, nullptr, 0.f, 0.f);
      inorm_stats<<<BB*CCH, 256, 0, stream>>>(dZ, stats);
      float ai = sqrtf((l+1.f)/(l+2.f));
      float bi = sqrtf((float)l/(float)(l+1));
      conv3x3<1><<<cgrid, 256, 0, stream>>>(
          dZ, Wt + (size_t)l*CCH*CCH*9, zbase + (size_t)l*LSTRIDE,
          stats,
          (l>0) ? zbase + (size_t)(l-1)*LSTRIDE : nullptr,
          (l==NL-1) ? X : nullptr,
          (l==0) ? X0 : nullptr,
          ai, bi);
    }
    back_scan<<<LSTRIDE/256, 256, 0, stream>>>(zbase, out0);
  }
}

// Round 3
// 2890.592 us; speedup vs baseline: 2.8246x; 2.8246x over previous
//
#include <hip/hip_runtime.h>
#include <math.h>

// ---------------- problem constants ----------------
#define HC 96
#define WC 96
#define CCH 64
#define BB 8
#define NL 8
#define IMG (HC*WC)                 // 9216
#define LSTRIDE (BB*CCH*IMG)        // 4,718,592
#define EPS 1e-5f

// padded-chunked NHWC bf16 layout: [b][ch2][y:98][x:98][ic:32]
#define PY 98
#define PX 98
#define ICH 32
#define PLANE (PY*PX*ICH)           // 307,328
#define PL (BB*2*PLANE)             // 4,917,248 els per layer tensor
#define APK_L (2*9*2*64*32)         // 73,728 els per layer per direction

typedef __bf16 bf16;
typedef bf16 bf16x8 __attribute__((ext_vector_type(8)));
typedef float f32x4 __attribute__((ext_vector_type(4)));

__device__ __forceinline__ float a_of(int i){ return sqrtf((i+1.f)/(i+2.f)); }
__device__ __forceinline__ float b_of(int i){ return sqrtf((float)i/(float)(i+1)); }

// ---------------------------------------------------------------------------
// Split weights into hi/lo bf16 planes, frag-friendly layout:
// apX[l][ch][tap][rep][oc64][ic32]. fwd: K[l][oc][ic][tap]; bwd: K[l][ic][oc][8-tap].
__global__ void pack_weights(const float* __restrict__ K,
                             bf16* __restrict__ apf, bf16* __restrict__ apb){
  int idx = blockIdx.x*256 + threadIdx.x;          // NL*9*64*64
  if (idx >= NL*9*64*64) return;
  int ic = idx & 63, oc = (idx>>6) & 63;
  int tap = (idx>>12) % 9, l = idx/(4096*9);
  float wf = K[(((size_t)l*64 + oc)*64 + ic)*9 + tap];
  float wb = K[(((size_t)l*64 + ic)*64 + oc)*9 + (8-tap)];
  int ch = ic>>5, ic5 = ic&31;
  size_t base = (size_t)l*APK_L + ((size_t)((ch*9 + tap)*2)*64 + oc)*32 + ic5;
  bf16 fh = (bf16)wf;
  apf[base] = fh; apf[base + 64*32] = (bf16)(wf - (float)fh);
  bf16 bh = (bf16)wb;
  apb[base] = bh; apb[base + 64*32] = (bf16)(wb - (float)bh);
}

// ---------------------------------------------------------------------------
// Fix-iter 0 constant-folded: Yf closed form from X, X0; writes padded NHWC bf16.
// LDS transpose so both global reads and writes are coalesced.
__global__ __launch_bounds__(256) void init_yf_t(const float* __restrict__ X,
                                                 const float* __restrict__ X0,
                                                 bf16* __restrict__ yfq){
  __shared__ float LX[64][97];
  __shared__ float L0[64][97];
  int b = blockIdx.y, y = blockIdx.x;
  for (int i = threadIdx.x; i < 64*96; i += 256){
    int c = i/96, x = i%96;
    LX[c][x] = X[(((size_t)b*64 + c)*96 + y)*96 + x];
    L0[c][x] = X0[((size_t)c*96 + y)*96 + x];
  }
  __syncthreads();
  for (int j = threadIdx.x; j < 96*64; j += 256){
    int x = j>>6, c = j&63;
    float xv = LX[c][x], x0v = L0[c][x];
    size_t eoff = ((size_t)(b*2 + (c>>5))*PY + (y+1))*(size_t)PX*ICH
                + (size_t)(x+1)*ICH + (c&31);
    float yf = 0.f;
#pragma unroll
    for (int i = 0; i < NL; i++){
      float yv = (i==0 ? x0v : 0.f) + (i==NL-1 ? xv : 0.f);
      yf = a_of(i)*(b_of(i)*yf + yv);
      yfq[(size_t)i*PL + eoff] = (bf16)yf;
    }
  }
}

// ---------------------------------------------------------------------------
// Backward scan in place over padded bf16 Yf->Z (pads are 0 and map to 0).
__global__ __launch_bounds__(256) void back_scan_q(bf16* __restrict__ buf){
  size_t base = ((size_t)blockIdx.x*256 + threadIdx.x)*8;
  float c[8];
#pragma unroll
  for (int e=0;e<8;e++) c[e]=0.f;
#pragma unroll
  for (int l = NL-1; l >= 0; l--){
    float al = a_of(l);
    uint4 v = *(const uint4*)(buf + (size_t)l*PL + base);
    bf16* h = (bf16*)&v;
    uint4 o; bf16* ho = (bf16*)&o;
#pragma unroll
    for (int e=0;e<8;e++){
      float z = al*(al*c[e] + (float)h[e]);
      ho[e] = (bf16)z; c[e] = z;
    }
    *(uint4*)(buf + (size_t)l*PL + base) = o;
  }
}

// Final backward scan: fp32 NCHW in zbase (d_out), emits out0 = Z[7].
__global__ __launch_bounds__(256) void back_scan_final(float* __restrict__ zbase,
                                                       float* __restrict__ out0){
  int idx = blockIdx.x*256 + threadIdx.x;
  float c = 0.f;
#pragma unroll
  for (int i = NL-1; i >= 0; i--){
    float ai = a_of(i);
    float z = ai*(ai*c + zbase[(size_t)i*LSTRIDE + idx]);
    zbase[(size_t)i*LSTRIDE + idx] = z;
    if (i == NL-1) out0[idx] = z;
    c = z;
  }
}

// ---------------------------------------------------------------------------
// Instance-norm stats over dZf (NHWC fp32): partial sums + device atomics.
__global__ __launch_bounds__(256) void stats_partial(const float* __restrict__ dZf,
                                                     float* __restrict__ acc){
  int b = blockIdx.y, slab = blockIdx.x;
  int oc = threadIdx.x & 63, pg = threadIdx.x >> 6;
  float s = 0.f, s2 = 0.f;
  for (int r = 0; r < 8; r++){
    int y = slab*8 + r;
    const float* row = dZf + (((size_t)b*96 + y)*96)*64;
    for (int xx = pg; xx < 96; xx += 4){
      float v = row[(size_t)xx*64 + oc];
      s += v; s2 += v*v;
    }
  }
  __shared__ float rs[256], rs2[256];
  rs[threadIdx.x] = s; rs2[threadIdx.x] = s2;
  __syncthreads();
  if (threadIdx.x < 64){
    s  = rs[oc] + rs[64+oc] + rs[128+oc] + rs[192+oc];
    s2 = rs2[oc] + rs2[64+oc] + rs2[128+oc] + rs2[192+oc];
    atomicAdd(&acc[(b*64 + oc)*2], s);
    atomicAdd(&acc[(b*64 + oc)*2 + 1], s2);
  }
}

__global__ void stat_fin(float* __restrict__ acc, float2* __restrict__ st){
  int bc = threadIdx.x;   // 512
  float s = acc[bc*2], s2 = acc[bc*2+1];
  float m = s*(1.f/IMG);
  float v = s2*(1.f/IMG) - m*m;
  if (v < 0.f) v = 0.f;
  st[bc] = make_float2(m, rsqrtf(v + EPS));
  acc[bc*2] = 0.f; acc[bc*2+1] = 0.f;   // re-zero for next layer-step
}

// ---------------------------------------------------------------------------
// Normalize + leaky-relu + quantize to padded NHWC bf16 (pads untouched/zero).
__global__ __launch_bounds__(256) void norm_cvt(const float* __restrict__ dZf,
                                                const float2* __restrict__ st,
                                                bf16* __restrict__ dzq){
  int i4 = blockIdx.x*256 + threadIdx.x;   // LSTRIDE/4
  size_t e = (size_t)i4*4;
  int oc = (int)(e & 63);
  size_t px = e >> 6;
  int x = (int)(px % 96); size_t t = px / 96;
  int y = (int)(t % 96);  int b = (int)(t / 96);
  const float* p = dZf + e;
  union { uint2 v; unsigned short u[4]; } o;
#pragma unroll
  for (int k=0;k<4;k++){
    float2 mr = st[b*64 + oc + k];
    float v = (p[k] - mr.x)*mr.y;
    v = (v >= 0.f) ? v : 0.2f*v;
    bf16 h = (bf16)v;
    o.u[k] = *(unsigned short*)&h;
  }
  size_t off = ((size_t)(b*2 + (oc>>5))*PY + (y+1))*(size_t)PX*ICH
             + (size_t)(x+1)*ICH + (oc&31);
  *(uint2*)(dzq + off) = o.v;
}

// ---------------------------------------------------------------------------
// MFMA implicit-GEMM 3x3 conv, pad=1, 2-pass split weights (Wh+Wl)*bf16(in).
// Block: 64 oc x (2 rows x 96 cols); wave = 4 M-tiles x 3 N-tiles.
// MODE 0: -> dZf (NHWC fp32, via LDS transpose)
// MODE 1: yv=-acc(+X/+X0); yf=a*(b*prev_q+yv) -> Yfq bf16 padded (transpose)
// MODE 2: same math fp32, direct NCHW stores to zbase (final iteration)
template<int MODE>
__global__ __launch_bounds__(256, 2) void conv_mfma(
    const bf16* __restrict__ inq, const bf16* __restrict__ apk,
    float* __restrict__ outF,
    bf16* __restrict__ yfq_out, const bf16* __restrict__ yfq_prev,
    float* __restrict__ zb_out, const float* __restrict__ zb_prev,
    const float* __restrict__ Xadd, const float* __restrict__ X0add,
    float a_i, float b_i)
{
  __shared__ __align__(16) char smem[25088 + 24576];
  bf16* Bb = (bf16*)smem;                  // [4][98][32] input rows
  bf16* Ab = (bf16*)(smem + 25088);        // [3 taps][2 rep][64][32]

  const int rowg = blockIdx.x, b = blockIdx.y;
  const int y0 = rowg*2;
  const int tid = threadIdx.x;
  const int w = tid>>6, lane = tid&63;
  const int n16 = lane&15, q = lane>>4;
  const int wr = w>>1, wcol = (w&1)*48;
  const int yg = y0 + wr;

  f32x4 acc[4][3];
#pragma unroll
  for (int a=0;a<4;a++)
#pragma unroll
    for (int c=0;c<3;c++){ f32x4 z = {0.f,0.f,0.f,0.f}; acc[a][c] = z; }

  for (int ch = 0; ch < 2; ch++){
    __syncthreads();
    { // stage 4 padded rows x 98 cols x 32 ic (contiguous copy)
      const uint4* src = (const uint4*)(inq + (size_t)(b*2 + ch)*PLANE
                                            + (size_t)y0*PX*ICH);
      uint4* dst = (uint4*)Bb;
      for (int i = tid; i < 1568; i += 256) dst[i] = src[i];
    }
    for (int tg = 0; tg < 3; tg++){       // tap row groups (ky = tg)
      __syncthreads();
      { // stage 3 taps x 2 reps x 64 oc x 32 ic of weights
        const uint4* src = (const uint4*)(apk + (size_t)ch*36864 + (size_t)tg*3*4096);
        uint4* dst = (uint4*)Ab;
        for (int i = tid; i < 1536; i += 256) dst[i] = src[i];
      }
      __syncthreads();
#pragma unroll
      for (int tj = 0; tj < 3; tj++){     // kx = tj
        const int ky = tg, kx = tj;
        bf16x8 Ah[4], Al[4];
#pragma unroll
        for (int mt=0;mt<4;mt++){
          Ah[mt] = *(const bf16x8*)(Ab + ((size_t)(tj*2 + 0)*64 + mt*16 + n16)*32 + q*8);
          Al[mt] = *(const bf16x8*)(Ab + ((size_t)(tj*2 + 1)*64 + mt*16 + n16)*32 + q*8);
        }
        bf16x8 Bf[3];
#pragma unroll
        for (int nt=0;nt<3;nt++)
          Bf[nt] = *(const bf16x8*)(Bb + ((size_t)(wr + ky)*PX + wcol + nt*16 + n16 + kx)*ICH + q*8);
#pragma unroll
        for (int nt=0;nt<3;nt++)
#pragma unroll
          for (int mt=0;mt<4;mt++)
            acc[mt][nt] = __builtin_amdgcn_mfma_f32_16x16x32_bf16(Ah[mt], Bf[nt], acc[mt][nt], 0,0,0);
#pragma unroll
        for (int nt=0;nt<3;nt++)
#pragma unroll
          for (int mt=0;mt<4;mt++)
            acc[mt][nt] = __builtin_amdgcn_mfma_f32_16x16x32_bf16(Al[mt], Bf[nt], acc[mt][nt], 0,0,0);
      }
    }
  }

  // ---------------- epilogue ----------------
  if (MODE >= 1){   // yv = -acc (+X at l=7) (+X0 at l=0); coalesced adds (x = lanes)
#pragma unroll
    for (int mt=0;mt<4;mt++)
#pragma unroll
      for (int nt=0;nt<3;nt++){
        const int x = wcol + nt*16 + n16;
#pragma unroll
        for (int r=0;r<4;r++){
          const int oc = mt*16 + q*4 + r;
          float v = -acc[mt][nt][r];
          if (Xadd)  v += Xadd[(((size_t)b*64 + oc)*96 + yg)*96 + x];
          if (X0add) v += X0add[((size_t)oc*96 + yg)*96 + x];
          acc[mt][nt][r] = v;
        }
      }
  }
  if (MODE == 2){   // final iter: fused forward scan, fp32 NCHW stores
#pragma unroll
    for (int mt=0;mt<4;mt++)
#pragma unroll
      for (int nt=0;nt<3;nt++){
        const int x = wcol + nt*16 + n16;
#pragma unroll
        for (int r=0;r<4;r++){
          const int oc = mt*16 + q*4 + r;
          size_t idx = (((size_t)b*64 + oc)*96 + yg)*96 + x;
          float prev = zb_prev[idx];
          zb_out[idx] = a_i*(b_i*prev + acc[mt][nt][r]);
        }
      }
    return;
  }

  __syncthreads();                        // all waves done with Bb/Ab
  float* T = (float*)smem + w*1584;       // per-wave 48 x 33 fp32 transpose tile
#pragma unroll
  for (int h=0; h<2; h++){                // oc halves of 32
#pragma unroll
    for (int mt2=0; mt2<2; mt2++)
#pragma unroll
      for (int nt=0;nt<3;nt++)
#pragma unroll
        for (int r=0;r<4;r++)
          T[(nt*16 + n16)*33 + mt2*16 + q*4 + r] = acc[2*h + mt2][nt][r];
    for (int f = lane; f < 384; f += 64){
      int px = f>>3, c4 = (f&7)*4;
      float vv[4];
#pragma unroll
      for (int k=0;k<4;k++) vv[k] = T[px*33 + c4 + k];
      int x = wcol + px;
      if (MODE == 0){
        float4 val = make_float4(vv[0], vv[1], vv[2], vv[3]);
        *(float4*)(outF + ((((size_t)b*96 + yg)*96 + x)*64 + h*32 + c4)) = val;
      } else {
        size_t off = ((size_t)(b*2 + h)*PY + (yg+1))*(size_t)PX*ICH
                   + (size_t)(x+1)*ICH + c4;
        uint2 pv = *(const uint2*)(yfq_prev + off);
        bf16* ph = (bf16*)&pv;
        union { uint2 v; unsigned short u[4]; } o;
#pragma unroll
        for (int k=0;k<4;k++){
          float yf = a_i*(b_i*(float)ph[k] + vv[k]);
          bf16 hh = (bf16)yf;
          o.u[k] = *(unsigned short*)&hh;
        }
        *(uint2*)(yfq_out + off) = o.v;
      }
    }
  }
}

// ---------------------------------------------------------------------------
extern "C" void kernel_launch(void* const* d_in, const int* in_sizes, int n_in,
                              void* d_out, int out_size, void* d_ws, size_t ws_size,
                              hipStream_t stream) {
  const float* X  = (const float*)d_in[0];
  const float* K  = (const float*)d_in[1];
  const float* X0 = (const float*)d_in[2];

  float* out0  = (float*)d_out;
  float* zbase = out0 + LSTRIDE;

  char* ws = (char*)d_ws;
  float*  statacc = (float*)ws;                         // 1024 f
  float2* st      = (float2*)(ws + 4096);               // 512 f2
  bf16*   apf     = (bf16*)(ws + 8192);
  bf16*   apb     = apf + (size_t)NL*APK_L;
  bf16*   Zq      = apb + (size_t)NL*APK_L;             // 8*PL (doubles as Yfq)
  bf16*   dZq     = Zq + (size_t)NL*PL;                 // PL
  float*  dZf     = (float*)(dZq + PL);                 // LSTRIDE f

  hipMemsetAsync(statacc, 0, 8192, stream);
  hipMemsetAsync(Zq, 0, (size_t)(NL+1)*PL*2, stream);   // zero pads (Zq + dZq)

  pack_weights<<<(NL*9*4096 + 255)/256, 256, 0, stream>>>(K, apf, apb);
  init_yf_t<<<dim3(HC, BB), 256, 0, stream>>>(X, X0, Zq);
  back_scan_q<<<PL/8/256, 256, 0, stream>>>(Zq);

  for (int it = 1; it <= 3; it++){
    for (int l = 0; l < NL; l++){
      conv_mfma<0><<<dim3(48,8),256,0,stream>>>(
          Zq + (size_t)l*PL, apf + (size_t)l*APK_L,
          dZf, nullptr, nullptr, nullptr, nullptr, nullptr, nullptr, 0.f, 0.f);
      stats_partial<<<dim3(12,8),256,0,stream>>>(dZf, statacc);
      stat_fin<<<1,512,0,stream>>>(statacc, st);
      norm_cvt<<<LSTRIDE/1024,256,0,stream>>>(dZf, st, dZq);
      float ai = sqrtf((l+1.f)/(l+2.f)), bi = sqrtf((float)l/(float)(l+1));
      if (it < 3)
        conv_mfma<1><<<dim3(48,8),256,0,stream>>>(
            dZq, apb + (size_t)l*APK_L,
            nullptr, Zq + (size_t)l*PL, Zq + (size_t)(l>0?l-1:0)*PL,
            nullptr, nullptr,
            (l==NL-1)?X:nullptr, (l==0)?X0:nullptr, ai, bi);
      else
        conv_mfma<2><<<dim3(48,8),256,0,stream>>>(
            dZq, apb + (size_t)l*APK_L,
            nullptr, nullptr, nullptr,
            zbase + (size_t)l*LSTRIDE, zbase + (size_t)(l>0?l-1:0)*LSTRIDE,
            (l==NL-1)?X:nullptr, (l==0)?X0:nullptr, ai, bi);
    }
    if (it < 3) back_scan_q<<<PL/8/256,256,0,stream>>>(Zq);
    else        back_scan_final<<<LSTRIDE/256,256,0,stream>>>(zbase, out0);
  }
}